// Round 8
// baseline (463.787 us; speedup 1.0000x reference)
//
#include <hip/hip_runtime.h>
#include <math.h>

#define BN 4
#define DD 256
#define LL 4096
#define NS 16
#define NCH 32   // scan chunks
#define CT 128   // chunk length (NCH*CT == LL)
#define LOG2E 1.4426950408889634f

typedef __bf16 bf16x8 __attribute__((ext_vector_type(8)));
typedef float f32x4 __attribute__((ext_vector_type(4)));

__device__ __forceinline__ float softplus_f(float v) {
  return v > 20.f ? v : log1pf(__expf(v));
}
__device__ __forceinline__ float silu_f(float v) {
  return v / (1.f + __expf(-v));
}

// ---------------- K1: MFMA bf16 GEMM with inline f32->bf16 conversion ----------------
__global__ __launch_bounds__(256) void k1_mfma(
    const float* __restrict__ W, const float* __restrict__ u,
    float* __restrict__ xpre, float* __restrict__ zb) {
  __shared__ float Af[128 * 36];   // [e][k] f32, stride 36
  __shared__ float Bf[32 * 68];    // [k][l] f32, stride 68
  const int l0 = blockIdx.x * 64;
  const int e0 = blockIdx.y * 128;
  const int b  = blockIdx.z;
  const int tid = threadIdx.x;
  const int lane = tid & 63, w = tid >> 6;
  const int m16 = lane & 15, quad = lane >> 4;

  f32x4 acc[2][4];
#pragma unroll
  for (int i = 0; i < 2; ++i)
#pragma unroll
    for (int j = 0; j < 4; ++j) acc[i][j] = (f32x4){0.f, 0.f, 0.f, 0.f};

  const float* Ub = u + (size_t)b * DD * LL;

  for (int k0 = 0; k0 < DD; k0 += 32) {
    if (k0) __syncthreads();
#pragma unroll
    for (int it = 0; it < 4; ++it) {
      int f4 = tid + it * 256;
      int e = f4 >> 3, kq = f4 & 7;
      *(float4*)&Af[e * 36 + kq * 4] =
          *(const float4*)(W + (size_t)(e0 + e) * DD + k0 + kq * 4);
    }
#pragma unroll
    for (int it = 0; it < 2; ++it) {
      int f4 = tid + it * 256;
      int kk = f4 >> 4, lq = f4 & 15;
      *(float4*)&Bf[kk * 68 + lq * 4] =
          *(const float4*)(Ub + (size_t)(k0 + kk) * LL + l0 + lq * 4);
    }
    __syncthreads();
    bf16x8 afr[2], bfr[4];
#pragma unroll
    for (int te = 0; te < 2; ++te) {
      const float* src = &Af[(w * 32 + te * 16 + m16) * 36 + quad * 8];
      bf16x8 t;
#pragma unroll
      for (int j = 0; j < 8; ++j) t[j] = (__bf16)src[j];
      afr[te] = t;
    }
#pragma unroll
    for (int tl = 0; tl < 4; ++tl) {
      bf16x8 t;
#pragma unroll
      for (int j = 0; j < 8; ++j) t[j] = (__bf16)Bf[(quad * 8 + j) * 68 + tl * 16 + m16];
      bfr[tl] = t;
    }
#pragma unroll
    for (int te = 0; te < 2; ++te)
#pragma unroll
      for (int tl = 0; tl < 4; ++tl)
        acc[te][tl] = __builtin_amdgcn_mfma_f32_16x16x32_bf16(afr[te], bfr[tl], acc[te][tl], 0, 0, 0);
  }

#pragma unroll
  for (int te = 0; te < 2; ++te) {
#pragma unroll
    for (int tl = 0; tl < 4; ++tl) {
      int col = l0 + tl * 16 + m16;
#pragma unroll
      for (int r = 0; r < 4; ++r) {
        int e = e0 + w * 32 + te * 16 + quad * 4 + r;
        float v = acc[te][tl][r];
        if (e < DD) xpre[((size_t)b * DD + e) * LL + col] = v;
        else        zb[((size_t)b * DD + (e - DD)) * LL + col] = v;
      }
    }
  }
}

// ---------------- K2: depthwise conv == 3-tap along d, weights per l ----------------
__global__ __launch_bounds__(256) void k2_conv(
    const float* __restrict__ xpre, const float* __restrict__ cw,
    const float* __restrict__ cb, float* __restrict__ xo) {
  const int bd = blockIdx.x;       // b*256 + d
  const int d = bd & 255;
  const size_t row = (size_t)bd * LL;
  const float* r1 = xpre + row;
  const bool has0 = d > 0, has2 = d < DD - 1;
  for (int j = threadIdx.x; j < LL; j += 256) {
    float w0 = cw[j * 9 + 3], w1 = cw[j * 9 + 4], w2 = cw[j * 9 + 5];
    float v = cb[j] + r1[j] * w1;
    if (has0) v += r1[j - LL] * w0;
    if (has2) v += r1[j + LL] * w2;
    xo[row + j] = v;
  }
}

// ---------------- K3: x_proj GEMM, 6 rows/block, no LDS / no barriers ----------
__global__ __launch_bounds__(256) void k3_xproj(
    const float* __restrict__ xc,
    const float* __restrict__ xpw, const float* __restrict__ xpwB,
    float* __restrict__ dtr, float* __restrict__ gB, float* __restrict__ gC) {
  const int tid = threadIdx.x;
  const int l   = blockIdx.x * 256 + tid;
  const int b   = blockIdx.y;
  const int zz  = blockIdx.z;            // dir*8 + rg
  const int dir = zz >> 3, rg = zz & 7;
  const int rbase = rg * 6;
  const float* W = (dir ? xpwB : xpw) + (size_t)rbase * DD;   // 6 rows x 256
  const float* xcol = xc + (size_t)b * DD * LL + l;

  float acc[6] = {0.f, 0.f, 0.f, 0.f, 0.f, 0.f};

#pragma unroll 8
  for (int d = 0; d < DD; ++d) {
    float xv = xcol[(size_t)d * LL];
#pragma unroll
    for (int i = 0; i < 6; ++i) acc[i] += W[i * DD + d] * xv;
  }

  const size_t ob = ((size_t)dir * BN + b);
#pragma unroll
  for (int i = 0; i < 6; ++i) {
    int r = rbase + i;
    if (r < 16)
      dtr[(ob * 16 + r) * LL + l] = acc[i];
    else if (r < 32)
      gB[(ob * NS + (r - 16)) * LL + l] = acc[i];
    else
      gC[(ob * NS + (r - 32)) * LL + l] = acc[i];
  }
}

// ---------------- K3b: dt_proj + softplus -> gdelta; dtr register-cached ----------
__global__ __launch_bounds__(256) void k3b_dtproj(
    const float* __restrict__ dtr,
    const float* __restrict__ dtw, const float* __restrict__ dtwB,
    const float* __restrict__ dtb,
    float* __restrict__ gdelta) {
  const int tid = threadIdx.x;
  const int l   = blockIdx.x * 256 + tid;
  const int b   = blockIdx.y & 3;
  const int dir = blockIdx.y >> 2;
  const int d0  = blockIdx.z * 64;
  const size_t ob = ((size_t)dir * BN + b);
  const float* dw = (dir ? dtwB : dtw);

  float tr[16];
#pragma unroll
  for (int r = 0; r < 16; ++r) tr[r] = dtr[(ob * 16 + r) * LL + l];

#pragma unroll 4
  for (int d = d0; d < d0 + 64; ++d) {
    float acc = dtb[d];
#pragma unroll
    for (int r = 0; r < 16; ++r) acc += dw[d * 16 + r] * tr[r];
    gdelta[(ob * DD + d) * LL + l] = softplus_f(acc);
  }
}

// ---------------- K4: scan pass A — zero LDS, exp2-folded An ----------------
__global__ __launch_bounds__(256) void k4_scanA(
    const float* __restrict__ gdelta, const float* __restrict__ x,
    const float* __restrict__ gB,
    const float* __restrict__ Alog, const float* __restrict__ AlogB,
    float* __restrict__ Pbuf, float* __restrict__ qbuf) {
  const int s = blockIdx.x;
  const int dbase = blockIdx.y * 16;
  const int dir = blockIdx.z >> 2, b = blockIdx.z & 3;
  const int t0 = s * CT;
  const int tid = threadIdx.x;
  const int g = tid >> 4, n = tid & 15;
  const int d = dbase + g;
  const size_t ob = ((size_t)dir * BN + b);
  const float An2 = -__expf((dir ? AlogB : Alog)[d * NS + n]) * LOG2E;
  const float* dlrow = gdelta + (ob * DD + d) * LL + t0;
  const float* xrow  = x + ((size_t)b * DD + d) * LL;
  const float* Brow  = gB + (ob * NS + n) * LL + t0;
  float h = 0.f, S = 0.f;
#pragma unroll 8
  for (int jb = 0; jb < CT; jb += 4) {
    float4 dl4 = *(const float4*)(dlrow + jb);
    float4 x4;
    if (dir == 0) {
      x4 = *(const float4*)(xrow + t0 + jb);
    } else {
      float4 t = *(const float4*)(xrow + LL - 4 - t0 - jb);
      x4 = make_float4(t.w, t.z, t.y, t.x);
    }
    float4 B4 = *(const float4*)(Brow + jb);
    h = h * exp2f(dl4.x * An2) + dl4.x * x4.x * B4.x;
    h = h * exp2f(dl4.y * An2) + dl4.y * x4.y * B4.y;
    h = h * exp2f(dl4.z * An2) + dl4.z * x4.z * B4.z;
    h = h * exp2f(dl4.w * An2) + dl4.w * x4.w * B4.w;
    S += dl4.x + dl4.y + dl4.z + dl4.w;
  }
  const size_t pidx = ((ob * DD + d) * NCH + s) * NS + n;
  Pbuf[pidx] = exp2f(An2 * S);
  qbuf[pidx] = h;
}

// ---------------- K6: scan pass C — inline middle scan, direct-global B/C,
//                     b128 ylds writes, exp2-folded An ----------------
__global__ __launch_bounds__(256) void k6_scanC(
    const float* __restrict__ gdelta, const float* __restrict__ x,
    const float* __restrict__ gB, const float* __restrict__ gC,
    const float* __restrict__ zb,
    const float* __restrict__ Alog, const float* __restrict__ AlogB,
    const float* __restrict__ Dvec, const float* __restrict__ DvecB,
    const float* __restrict__ Pbuf, const float* __restrict__ qbuf,
    float* __restrict__ y, float* __restrict__ yb) {
  __shared__ float ylds[16 * 16 * 12];   // [(g*16+n)][t' 0..7], stride 12 (16B-aligned)
  const int s = blockIdx.x;
  const int dbase = blockIdx.y * 16;
  const int dir = blockIdx.z >> 2, b = blockIdx.z & 3;
  const int t0 = s * CT;
  const int tid = threadIdx.x;
  const int g = tid >> 4, n = tid & 15;
  const int d = dbase + g;
  const size_t ob = ((size_t)dir * BN + b);
  const float An2 = -__expf((dir ? AlogB : Alog)[d * NS + n]) * LOG2E;
  const float Dd = (dir ? DvecB : Dvec)[d];

  // inline middle scan: exclusive prefix over chunks 0..s-1
  const size_t pbase = ((ob * DD + d) * NCH) * NS + n;
  float h = 0.f;
  for (int cs = 0; cs < s; ++cs) {
    float Pv = Pbuf[pbase + (size_t)cs * NS];
    float qv = qbuf[pbase + (size_t)cs * NS];
    h = h * Pv + qv;
  }

  float* dst = (dir ? yb : y) + ((size_t)b * DD + d) * LL;
  const float* dlrow = gdelta + (ob * DD + d) * LL + t0;
  const float* xrow  = x + ((size_t)b * DD + d) * LL;
  const float* zrow  = zb + ((size_t)b * DD + d) * LL;
  const float* Brow  = gB + (ob * NS + n) * LL + t0;
  const float* Crow  = gC + (ob * NS + n) * LL + t0;
  const int yrow = (g * 16 + n) * 12;
  const int half = n >> 3, j8 = n & 7;

  for (int jb = 0; jb < CT; jb += 8) {
#pragma unroll
    for (int q = 0; q < 2; ++q) {
      int j4 = jb + q * 4;
      float4 dl4 = *(const float4*)(dlrow + j4);
      float4 x4;
      if (dir == 0) {
        x4 = *(const float4*)(xrow + t0 + j4);
      } else {
        float4 t = *(const float4*)(xrow + LL - 4 - t0 - j4);
        x4 = make_float4(t.w, t.z, t.y, t.x);
      }
      float4 B4 = *(const float4*)(Brow + j4);
      float4 C4 = *(const float4*)(Crow + j4);
      float4 hc;
      h = h * exp2f(dl4.x * An2) + (dl4.x * x4.x) * B4.x; hc.x = h * C4.x;
      h = h * exp2f(dl4.y * An2) + (dl4.y * x4.y) * B4.y; hc.y = h * C4.y;
      h = h * exp2f(dl4.z * An2) + (dl4.z * x4.z) * B4.z; hc.z = h * C4.z;
      h = h * exp2f(dl4.w * An2) + (dl4.w * x4.w) * B4.w; hc.w = h * C4.w;
      *(float4*)&ylds[yrow + q * 4] = hc;
    }
    // lane (half,j8): sum its 8 m-rows at t'=j8, combine halves by shuffle
    float ysum = 0.f;
#pragma unroll
    for (int m = 0; m < 8; ++m) ysum += ylds[(g * 16 + half * 8 + m) * 12 + j8];
    ysum += __shfl_xor(ysum, 8);
    if (half == 0) {
      int t = jb + j8;
      float xv = (dir == 0) ? xrow[t0 + t] : xrow[LL - 1 - (t0 + t)];
      float zv = zrow[t0 + t];
      dst[t0 + t] = (ysum + Dd * xv) * silu_f(zv);
    }
  }
}

// ---------------- K7: dual LayerNorm + double SiLU gate + flip-add ----------------
__global__ __launch_bounds__(256) void k7_final(
    const float* __restrict__ y, const float* __restrict__ yb,
    const float* __restrict__ zb,
    const float* __restrict__ lnw, const float* __restrict__ lnb,
    const float* __restrict__ ln1w, const float* __restrict__ ln1b,
    float* __restrict__ out) {
  __shared__ float sy[LL];
  __shared__ float syb[LL];
  __shared__ float rsum[4][4];
  const int row = blockIdx.x;
  const int tid = threadIdx.x;
  const size_t base = (size_t)row * LL;
  float s1y = 0.f, s2y = 0.f, s1b = 0.f, s2b = 0.f;
  for (int j = tid * 4; j < LL; j += 1024) {
    float4 v = *(const float4*)(y + base + j);
    *(float4*)&sy[j] = v;
    s1y += v.x + v.y + v.z + v.w;
    s2y += v.x * v.x + v.y * v.y + v.z * v.z + v.w * v.w;
    float4 w = *(const float4*)(yb + base + j);
    *(float4*)&syb[j] = w;
    s1b += w.x + w.y + w.z + w.w;
    s2b += w.x * w.x + w.y * w.y + w.z * w.z + w.w * w.w;
  }
#pragma unroll
  for (int m = 1; m < 64; m <<= 1) {
    s1y += __shfl_xor(s1y, m); s2y += __shfl_xor(s2y, m);
    s1b += __shfl_xor(s1b, m); s2b += __shfl_xor(s2b, m);
  }
  int wv = tid >> 6;
  if ((tid & 63) == 0) { rsum[wv][0] = s1y; rsum[wv][1] = s2y; rsum[wv][2] = s1b; rsum[wv][3] = s2b; }
  __syncthreads();
  float t1y = rsum[0][0] + rsum[1][0] + rsum[2][0] + rsum[3][0];
  float t2y = rsum[0][1] + rsum[1][1] + rsum[2][1] + rsum[3][1];
  float t1b = rsum[0][2] + rsum[1][2] + rsum[2][2] + rsum[3][2];
  float t2b = rsum[0][3] + rsum[1][3] + rsum[2][3] + rsum[3][3];
  const float inv = 1.f / (float)LL;
  float mY = t1y * inv; float vY = t2y * inv - mY * mY; float rY = rsqrtf(vY + 1e-5f);
  float mB = t1b * inv; float vB = t2b * inv - mB * mB; float rB = rsqrtf(vB + 1e-5f);
  for (int j = tid; j < LL; j += 256) {
    int jr = LL - 1 - j;
    float a  = (sy[j]  - mY) * rY * lnw[j]   + lnb[j];
    float g1 = silu_f(zb[base + j]);
    float bv = (syb[jr] - mB) * rB * ln1w[jr] + ln1b[jr];
    float g2 = silu_f(zb[base + jr]);
    out[base + j] = a * g1 + bv * g2;
  }
}

extern "C" void kernel_launch(void* const* d_in, const int* in_sizes, int n_in,
                              void* d_out, int out_size, void* d_ws, size_t ws_size,
                              hipStream_t stream) {
  const float* u     = (const float*)d_in[0];
  const float* inw   = (const float*)d_in[1];
  const float* cw    = (const float*)d_in[2];
  const float* cb    = (const float*)d_in[3];
  const float* xpw   = (const float*)d_in[4];
  const float* dtw   = (const float*)d_in[5];
  const float* dtb   = (const float*)d_in[6];
  const float* Alog  = (const float*)d_in[7];
  const float* Dv    = (const float*)d_in[8];
  const float* xpwB  = (const float*)d_in[9];
  const float* dtwB  = (const float*)d_in[10];
  const float* AlogB = (const float*)d_in[11];
  const float* DvB   = (const float*)d_in[12];
  const float* lnw   = (const float*)d_in[13];
  const float* lnb   = (const float*)d_in[14];
  const float* ln1w  = (const float*)d_in[15];
  const float* ln1b  = (const float*)d_in[16];
  float* out = (float*)d_out;

  float* ws = (float*)d_ws;
  const size_t SZ = (size_t)BN * DD * LL;        // 4,194,304 floats
  float* xpre   = ws;
  float* zb     = ws + SZ;
  float* xc     = ws + 2 * SZ;
  float* gdelta = ws + 3 * SZ;        // 2 dirs
  float* gB     = ws + 5 * SZ;
  float* gC     = gB + SZ / 8;
  float* Pbuf   = gC + SZ / 8;
  float* qbuf   = Pbuf + SZ / 4;
  float* ybbuf  = qbuf + SZ / 4;
  float* ybuf   = xpre;               // alias: xpre dead after k2
  float* dtr    = ybbuf;              // alias: dtr dead before k6 writes ybbuf

  k1_mfma<<<dim3(64, 4, 4), 256, 0, stream>>>(inw, u, xpre, zb);
  k2_conv<<<1024, 256, 0, stream>>>(xpre, cw, cb, xc);
  k3_xproj<<<dim3(16, 4, 16), 256, 0, stream>>>(xc, xpw, xpwB, dtr, gB, gC);
  k3b_dtproj<<<dim3(16, 8, 4), 256, 0, stream>>>(dtr, dtw, dtwB, dtb, gdelta);
  k4_scanA<<<dim3(NCH, 16, 8), 256, 0, stream>>>(gdelta, xc, gB, Alog, AlogB, Pbuf, qbuf);
  k6_scanC<<<dim3(NCH, 16, 8), 256, 0, stream>>>(gdelta, xc, gB, gC, zb, Alog, AlogB,
                                                 Dv, DvB, Pbuf, qbuf, ybuf, ybbuf);
  k7_final<<<1024, 256, 0, stream>>>(ybuf, ybbuf, zb, lnw, lnb, ln1w, ln1b, out);
}

// Round 9
// 323.845 us; speedup vs baseline: 1.4321x; 1.4321x over previous
//
#include <hip/hip_runtime.h>
#include <math.h>

#define BN 4
#define DD 256
#define LL 4096
#define NS 16
#define NCH 32   // scan chunks
#define CT 128   // chunk length (NCH*CT == LL)
#define SP 132   // CT + 4 pad
#define LOG2E 1.4426950408889634f

typedef __bf16 bf16x8 __attribute__((ext_vector_type(8)));
typedef float f32x4 __attribute__((ext_vector_type(4)));

__device__ __forceinline__ float softplus_f(float v) {
  return v > 20.f ? v : log1pf(__expf(v));
}
__device__ __forceinline__ float silu_f(float v) {
  return v / (1.f + __expf(-v));
}

// ---------------- K1: MFMA bf16 GEMM with inline f32->bf16 conversion ----------------
__global__ __launch_bounds__(256) void k1_mfma(
    const float* __restrict__ W, const float* __restrict__ u,
    float* __restrict__ xpre, float* __restrict__ zb) {
  __shared__ float Af[128 * 36];   // [e][k] f32, stride 36
  __shared__ float Bf[32 * 68];    // [k][l] f32, stride 68
  const int l0 = blockIdx.x * 64;
  const int e0 = blockIdx.y * 128;
  const int b  = blockIdx.z;
  const int tid = threadIdx.x;
  const int lane = tid & 63, w = tid >> 6;
  const int m16 = lane & 15, quad = lane >> 4;

  f32x4 acc[2][4];
#pragma unroll
  for (int i = 0; i < 2; ++i)
#pragma unroll
    for (int j = 0; j < 4; ++j) acc[i][j] = (f32x4){0.f, 0.f, 0.f, 0.f};

  const float* Ub = u + (size_t)b * DD * LL;

  for (int k0 = 0; k0 < DD; k0 += 32) {
    if (k0) __syncthreads();
#pragma unroll
    for (int it = 0; it < 4; ++it) {
      int f4 = tid + it * 256;
      int e = f4 >> 3, kq = f4 & 7;
      *(float4*)&Af[e * 36 + kq * 4] =
          *(const float4*)(W + (size_t)(e0 + e) * DD + k0 + kq * 4);
    }
#pragma unroll
    for (int it = 0; it < 2; ++it) {
      int f4 = tid + it * 256;
      int kk = f4 >> 4, lq = f4 & 15;
      *(float4*)&Bf[kk * 68 + lq * 4] =
          *(const float4*)(Ub + (size_t)(k0 + kk) * LL + l0 + lq * 4);
    }
    __syncthreads();
    bf16x8 afr[2], bfr[4];
#pragma unroll
    for (int te = 0; te < 2; ++te) {
      const float* src = &Af[(w * 32 + te * 16 + m16) * 36 + quad * 8];
      bf16x8 t;
#pragma unroll
      for (int j = 0; j < 8; ++j) t[j] = (__bf16)src[j];
      afr[te] = t;
    }
#pragma unroll
    for (int tl = 0; tl < 4; ++tl) {
      bf16x8 t;
#pragma unroll
      for (int j = 0; j < 8; ++j) t[j] = (__bf16)Bf[(quad * 8 + j) * 68 + tl * 16 + m16];
      bfr[tl] = t;
    }
#pragma unroll
    for (int te = 0; te < 2; ++te)
#pragma unroll
      for (int tl = 0; tl < 4; ++tl)
        acc[te][tl] = __builtin_amdgcn_mfma_f32_16x16x32_bf16(afr[te], bfr[tl], acc[te][tl], 0, 0, 0);
  }

#pragma unroll
  for (int te = 0; te < 2; ++te) {
#pragma unroll
    for (int tl = 0; tl < 4; ++tl) {
      int col = l0 + tl * 16 + m16;
#pragma unroll
      for (int r = 0; r < 4; ++r) {
        int e = e0 + w * 32 + te * 16 + quad * 4 + r;
        float v = acc[te][tl][r];
        if (e < DD) xpre[((size_t)b * DD + e) * LL + col] = v;
        else        zb[((size_t)b * DD + (e - DD)) * LL + col] = v;
      }
    }
  }
}

// ---------------- K2: depthwise conv == 3-tap along d, weights per l ----------------
__global__ __launch_bounds__(256) void k2_conv(
    const float* __restrict__ xpre, const float* __restrict__ cw,
    const float* __restrict__ cb, float* __restrict__ xo) {
  const int bd = blockIdx.x;       // b*256 + d
  const int d = bd & 255;
  const size_t row = (size_t)bd * LL;
  const float* r1 = xpre + row;
  const bool has0 = d > 0, has2 = d < DD - 1;
  for (int j = threadIdx.x; j < LL; j += 256) {
    float w0 = cw[j * 9 + 3], w1 = cw[j * 9 + 4], w2 = cw[j * 9 + 5];
    float v = cb[j] + r1[j] * w1;
    if (has0) v += r1[j - LL] * w0;
    if (has2) v += r1[j + LL] * w2;
    xo[row + j] = v;
  }
}

// ---------------- K3: x_proj GEMM, 6 rows/block, no LDS / no barriers ----------
__global__ __launch_bounds__(256) void k3_xproj(
    const float* __restrict__ xc,
    const float* __restrict__ xpw, const float* __restrict__ xpwB,
    float* __restrict__ dtr, float* __restrict__ gB, float* __restrict__ gC) {
  const int tid = threadIdx.x;
  const int l   = blockIdx.x * 256 + tid;
  const int b   = blockIdx.y;
  const int zz  = blockIdx.z;            // dir*8 + rg
  const int dir = zz >> 3, rg = zz & 7;
  const int rbase = rg * 6;
  const float* W = (dir ? xpwB : xpw) + (size_t)rbase * DD;   // 6 rows x 256
  const float* xcol = xc + (size_t)b * DD * LL + l;

  float acc[6] = {0.f, 0.f, 0.f, 0.f, 0.f, 0.f};

#pragma unroll 8
  for (int d = 0; d < DD; ++d) {
    float xv = xcol[(size_t)d * LL];
#pragma unroll
    for (int i = 0; i < 6; ++i) acc[i] += W[i * DD + d] * xv;
  }

  const size_t ob = ((size_t)dir * BN + b);
#pragma unroll
  for (int i = 0; i < 6; ++i) {
    int r = rbase + i;
    if (r < 16)
      dtr[(ob * 16 + r) * LL + l] = acc[i];
    else if (r < 32)
      gB[(ob * NS + (r - 16)) * LL + l] = acc[i];
    else
      gC[(ob * NS + (r - 32)) * LL + l] = acc[i];
  }
}

// ---------------- K3b: dt_proj + softplus -> gdelta; dtr register-cached ----------
__global__ __launch_bounds__(256) void k3b_dtproj(
    const float* __restrict__ dtr,
    const float* __restrict__ dtw, const float* __restrict__ dtwB,
    const float* __restrict__ dtb,
    float* __restrict__ gdelta) {
  const int tid = threadIdx.x;
  const int l   = blockIdx.x * 256 + tid;
  const int b   = blockIdx.y & 3;
  const int dir = blockIdx.y >> 2;
  const int d0  = blockIdx.z * 64;
  const size_t ob = ((size_t)dir * BN + b);
  const float* dw = (dir ? dtwB : dtw);

  float tr[16];
#pragma unroll
  for (int r = 0; r < 16; ++r) tr[r] = dtr[(ob * 16 + r) * LL + l];

#pragma unroll 4
  for (int d = d0; d < d0 + 64; ++d) {
    float acc = dtb[d];
#pragma unroll
    for (int r = 0; r < 16; ++r) acc += dw[d * 16 + r] * tr[r];
    gdelta[(ob * DD + d) * LL + l] = softplus_f(acc);
  }
}

// ---------------- K4: scan pass A — B staged in LDS; exp2-folded An ----------------
__global__ __launch_bounds__(256) void k4_scanA(
    const float* __restrict__ gdelta, const float* __restrict__ x,
    const float* __restrict__ gB,
    const float* __restrict__ Alog, const float* __restrict__ AlogB,
    float* __restrict__ Pbuf, float* __restrict__ qbuf) {
  __shared__ float sB[16 * SP];
  const int s = blockIdx.x;
  const int dbase = blockIdx.y * 16;
  const int dir = blockIdx.z >> 2, b = blockIdx.z & 3;
  const int t0 = s * CT;
  const int tid = threadIdx.x;

  for (int idx = tid; idx < 16 * 32; idx += 256) {
    int row = idx >> 5, q = idx & 31;
    *(float4*)&sB[row * SP + q * 4] =
        *(const float4*)(gB + (((size_t)dir * BN + b) * NS + row) * LL + t0 + q * 4);
  }
  __syncthreads();

  const int g = tid >> 4, n = tid & 15;
  const int d = dbase + g;
  const float An2 = -__expf((dir ? AlogB : Alog)[d * NS + n]) * LOG2E;
  const float* dlrow = gdelta + (((size_t)dir * BN + b) * DD + d) * LL + t0;
  const float* xrow  = x + ((size_t)b * DD + d) * LL;
  float h = 0.f, S = 0.f;
#pragma unroll 8
  for (int jb = 0; jb < CT; jb += 4) {
    float4 dl4 = *(const float4*)(dlrow + jb);
    float4 x4;
    if (dir == 0) {
      x4 = *(const float4*)(xrow + t0 + jb);
    } else {
      float4 t = *(const float4*)(xrow + LL - 4 - t0 - jb);
      x4 = make_float4(t.w, t.z, t.y, t.x);
    }
    float4 B4 = *(float4*)&sB[n * SP + jb];
    h = h * __builtin_amdgcn_exp2f(dl4.x * An2) + dl4.x * x4.x * B4.x;
    h = h * __builtin_amdgcn_exp2f(dl4.y * An2) + dl4.y * x4.y * B4.y;
    h = h * __builtin_amdgcn_exp2f(dl4.z * An2) + dl4.z * x4.z * B4.z;
    h = h * __builtin_amdgcn_exp2f(dl4.w * An2) + dl4.w * x4.w * B4.w;
    S += dl4.x + dl4.y + dl4.z + dl4.w;
  }
  const size_t pidx = ((((size_t)dir * BN + b) * DD + d) * NCH + s) * NS + n;
  Pbuf[pidx] = __builtin_amdgcn_exp2f(An2 * S);
  qbuf[pidx] = h;
}

// ---------------- K5: middle scan over chunks ----------------
__global__ __launch_bounds__(256) void k5_mid(
    const float* __restrict__ Pbuf, float* __restrict__ qbuf) {
  int id = blockIdx.x * 256 + threadIdx.x;
  int n = id & 15;
  int d = (id >> 4) & 255;
  int rb = id >> 12;
  size_t base = (((size_t)rb * DD + d) * NCH) * NS + n;
  float h = 0.f;
  for (int s = 0; s < NCH; ++s) {
    size_t idx = base + (size_t)s * NS;
    float Pv = Pbuf[idx];
    float qv = qbuf[idx];
    qbuf[idx] = h;
    h = h * Pv + qv;
  }
}

// ---------------- K6: scan pass C — staged B/C, stride-9 ylds, exp2-folded ----------
__global__ __launch_bounds__(256) void k6_scanC(
    const float* __restrict__ gdelta, const float* __restrict__ x,
    const float* __restrict__ gB, const float* __restrict__ gC,
    const float* __restrict__ zb,
    const float* __restrict__ Alog, const float* __restrict__ AlogB,
    const float* __restrict__ Dvec, const float* __restrict__ DvecB,
    const float* __restrict__ hstart,
    float* __restrict__ y, float* __restrict__ yb) {
  __shared__ float sB[16 * SP];
  __shared__ float sC[16 * SP];
  __shared__ float ylds[16 * 16 * 9];   // [(g*16+n)][t' 0..8], stride 9 (conflict-free)
  const int s = blockIdx.x;
  const int dbase = blockIdx.y * 16;
  const int dir = blockIdx.z >> 2, b = blockIdx.z & 3;
  const int t0 = s * CT;
  const int tid = threadIdx.x;

  for (int idx = tid; idx < 16 * 32; idx += 256) {
    int row = idx >> 5, q = idx & 31;
    *(float4*)&sB[row * SP + q * 4] =
        *(const float4*)(gB + (((size_t)dir * BN + b) * NS + row) * LL + t0 + q * 4);
    *(float4*)&sC[row * SP + q * 4] =
        *(const float4*)(gC + (((size_t)dir * BN + b) * NS + row) * LL + t0 + q * 4);
  }
  __syncthreads();

  const int g = tid >> 4, n = tid & 15;
  const int d = dbase + g;
  const float An2 = -__expf((dir ? AlogB : Alog)[d * NS + n]) * LOG2E;
  const float Dd = (dir ? DvecB : Dvec)[d];
  const size_t pidx = ((((size_t)dir * BN + b) * DD + d) * NCH + s) * NS + n;
  float h = hstart[pidx];
  float* dst = (dir ? yb : y) + ((size_t)b * DD + d) * LL;
  const float* dlrow = gdelta + (((size_t)dir * BN + b) * DD + d) * LL + t0;
  const float* xrow  = x + ((size_t)b * DD + d) * LL;
  const float* zrow  = zb + ((size_t)b * DD + d) * LL;
  const int yrow = (g * 16 + n) * 9;
  const int half = n >> 3, j8 = n & 7;

  for (int jb = 0; jb < CT; jb += 8) {
#pragma unroll
    for (int q = 0; q < 2; ++q) {
      int j4 = jb + q * 4;
      float4 dl4 = *(const float4*)(dlrow + j4);
      float4 x4;
      if (dir == 0) {
        x4 = *(const float4*)(xrow + t0 + j4);
      } else {
        float4 t = *(const float4*)(xrow + LL - 4 - t0 - j4);
        x4 = make_float4(t.w, t.z, t.y, t.x);
      }
      float4 B4 = *(float4*)&sB[n * SP + j4];
      float4 C4 = *(float4*)&sC[n * SP + j4];
      h = h * __builtin_amdgcn_exp2f(dl4.x * An2) + (dl4.x * x4.x) * B4.x; ylds[yrow + q * 4 + 0] = h * C4.x;
      h = h * __builtin_amdgcn_exp2f(dl4.y * An2) + (dl4.y * x4.y) * B4.y; ylds[yrow + q * 4 + 1] = h * C4.y;
      h = h * __builtin_amdgcn_exp2f(dl4.z * An2) + (dl4.z * x4.z) * B4.z; ylds[yrow + q * 4 + 2] = h * C4.z;
      h = h * __builtin_amdgcn_exp2f(dl4.w * An2) + (dl4.w * x4.w) * B4.w; ylds[yrow + q * 4 + 3] = h * C4.w;
    }
    float ysum = 0.f;
#pragma unroll
    for (int m = 0; m < 8; ++m) ysum += ylds[(g * 16 + half * 8 + m) * 9 + j8];
    ysum += __shfl_xor(ysum, 8);
    if (half == 0) {
      int t = jb + j8;
      float xv = (dir == 0) ? xrow[t0 + t] : xrow[LL - 1 - (t0 + t)];
      float zv = zrow[t0 + t];
      dst[t0 + t] = (ysum + Dd * xv) * silu_f(zv);
    }
  }
}

// ---------------- K7: dual LayerNorm + double SiLU gate + flip-add ----------------
__global__ __launch_bounds__(256) void k7_final(
    const float* __restrict__ y, const float* __restrict__ yb,
    const float* __restrict__ zb,
    const float* __restrict__ lnw, const float* __restrict__ lnb,
    const float* __restrict__ ln1w, const float* __restrict__ ln1b,
    float* __restrict__ out) {
  __shared__ float sy[LL];
  __shared__ float syb[LL];
  __shared__ float rsum[4][4];
  const int row = blockIdx.x;
  const int tid = threadIdx.x;
  const size_t base = (size_t)row * LL;
  float s1y = 0.f, s2y = 0.f, s1b = 0.f, s2b = 0.f;
  for (int j = tid * 4; j < LL; j += 1024) {
    float4 v = *(const float4*)(y + base + j);
    *(float4*)&sy[j] = v;
    s1y += v.x + v.y + v.z + v.w;
    s2y += v.x * v.x + v.y * v.y + v.z * v.z + v.w * v.w;
    float4 w = *(const float4*)(yb + base + j);
    *(float4*)&syb[j] = w;
    s1b += w.x + w.y + w.z + w.w;
    s2b += w.x * w.x + w.y * w.y + w.z * w.z + w.w * w.w;
  }
#pragma unroll
  for (int m = 1; m < 64; m <<= 1) {
    s1y += __shfl_xor(s1y, m); s2y += __shfl_xor(s2y, m);
    s1b += __shfl_xor(s1b, m); s2b += __shfl_xor(s2b, m);
  }
  int wv = tid >> 6;
  if ((tid & 63) == 0) { rsum[wv][0] = s1y; rsum[wv][1] = s2y; rsum[wv][2] = s1b; rsum[wv][3] = s2b; }
  __syncthreads();
  float t1y = rsum[0][0] + rsum[1][0] + rsum[2][0] + rsum[3][0];
  float t2y = rsum[0][1] + rsum[1][1] + rsum[2][1] + rsum[3][1];
  float t1b = rsum[0][2] + rsum[1][2] + rsum[2][2] + rsum[3][2];
  float t2b = rsum[0][3] + rsum[1][3] + rsum[2][3] + rsum[3][3];
  const float inv = 1.f / (float)LL;
  float mY = t1y * inv; float vY = t2y * inv - mY * mY; float rY = rsqrtf(vY + 1e-5f);
  float mB = t1b * inv; float vB = t2b * inv - mB * mB; float rB = rsqrtf(vB + 1e-5f);
  for (int j = tid; j < LL; j += 256) {
    int jr = LL - 1 - j;
    float a  = (sy[j]  - mY) * rY * lnw[j]   + lnb[j];
    float g1 = silu_f(zb[base + j]);
    float bv = (syb[jr] - mB) * rB * ln1w[jr] + ln1b[jr];
    float g2 = silu_f(zb[base + jr]);
    out[base + j] = a * g1 + bv * g2;
  }
}

extern "C" void kernel_launch(void* const* d_in, const int* in_sizes, int n_in,
                              void* d_out, int out_size, void* d_ws, size_t ws_size,
                              hipStream_t stream) {
  const float* u     = (const float*)d_in[0];
  const float* inw   = (const float*)d_in[1];
  const float* cw    = (const float*)d_in[2];
  const float* cb    = (const float*)d_in[3];
  const float* xpw   = (const float*)d_in[4];
  const float* dtw   = (const float*)d_in[5];
  const float* dtb   = (const float*)d_in[6];
  const float* Alog  = (const float*)d_in[7];
  const float* Dv    = (const float*)d_in[8];
  const float* xpwB  = (const float*)d_in[9];
  const float* dtwB  = (const float*)d_in[10];
  const float* AlogB = (const float*)d_in[11];
  const float* DvB   = (const float*)d_in[12];
  const float* lnw   = (const float*)d_in[13];
  const float* lnb   = (const float*)d_in[14];
  const float* ln1w  = (const float*)d_in[15];
  const float* ln1b  = (const float*)d_in[16];
  float* out = (float*)d_out;

  float* ws = (float*)d_ws;
  const size_t SZ = (size_t)BN * DD * LL;        // 4,194,304 floats
  float* xpre   = ws;
  float* zb     = ws + SZ;
  float* xc     = ws + 2 * SZ;
  float* gdelta = ws + 3 * SZ;        // 2 dirs
  float* gB     = ws + 5 * SZ;
  float* gC     = gB + SZ / 8;
  float* Pbuf   = gC + SZ / 8;
  float* qbuf   = Pbuf + SZ / 4;      // becomes hstart after k5_mid
  float* ybbuf  = qbuf + SZ / 4;
  float* ybuf   = xpre;               // alias: xpre dead after k2
  float* dtr    = ybbuf;              // alias: dtr dead before k6 writes ybbuf

  k1_mfma<<<dim3(64, 4, 4), 256, 0, stream>>>(inw, u, xpre, zb);
  k2_conv<<<1024, 256, 0, stream>>>(xpre, cw, cb, xc);
  k3_xproj<<<dim3(16, 4, 16), 256, 0, stream>>>(xc, xpw, xpwB, dtr, gB, gC);
  k3b_dtproj<<<dim3(16, 8, 4), 256, 0, stream>>>(dtr, dtw, dtwB, dtb, gdelta);
  k4_scanA<<<dim3(NCH, 16, 8), 256, 0, stream>>>(gdelta, xc, gB, Alog, AlogB, Pbuf, qbuf);
  k5_mid<<<128, 256, 0, stream>>>(Pbuf, qbuf);
  k6_scanC<<<dim3(NCH, 16, 8), 256, 0, stream>>>(gdelta, xc, gB, gC, zb, Alog, AlogB,
                                                 Dv, DvB, qbuf, ybuf, ybbuf);
  k7_final<<<1024, 256, 0, stream>>>(ybuf, ybbuf, zb, lnw, lnb, ln1w, ln1b, out);
}

// Round 10
// 311.475 us; speedup vs baseline: 1.4890x; 1.0397x over previous
//
#include <hip/hip_runtime.h>
#include <math.h>

#define BN 4
#define DD 256
#define LL 4096
#define NS 16
#define NCH 32   // scan chunks
#define CT 128   // chunk length (NCH*CT == LL)
#define SP 132   // CT + 4 pad
#define LOG2E 1.4426950408889634f

typedef __bf16 bf16x8 __attribute__((ext_vector_type(8)));
typedef float f32x4 __attribute__((ext_vector_type(4)));

__device__ __forceinline__ float softplus_f(float v) {
  return v > 20.f ? v : log1pf(__expf(v));
}
__device__ __forceinline__ float silu_f(float v) {
  return v / (1.f + __expf(-v));
}

// ---------------- K1: MFMA bf16 GEMM with inline f32->bf16 conversion ----------------
__global__ __launch_bounds__(256) void k1_mfma(
    const float* __restrict__ W, const float* __restrict__ u,
    float* __restrict__ xpre, float* __restrict__ zb) {
  __shared__ float Af[128 * 36];   // [e][k] f32, stride 36
  __shared__ float Bf[32 * 68];    // [k][l] f32, stride 68
  const int l0 = blockIdx.x * 64;
  const int e0 = blockIdx.y * 128;
  const int b  = blockIdx.z;
  const int tid = threadIdx.x;
  const int lane = tid & 63, w = tid >> 6;
  const int m16 = lane & 15, quad = lane >> 4;

  f32x4 acc[2][4];
#pragma unroll
  for (int i = 0; i < 2; ++i)
#pragma unroll
    for (int j = 0; j < 4; ++j) acc[i][j] = (f32x4){0.f, 0.f, 0.f, 0.f};

  const float* Ub = u + (size_t)b * DD * LL;

  for (int k0 = 0; k0 < DD; k0 += 32) {
    if (k0) __syncthreads();
#pragma unroll
    for (int it = 0; it < 4; ++it) {
      int f4 = tid + it * 256;
      int e = f4 >> 3, kq = f4 & 7;
      *(float4*)&Af[e * 36 + kq * 4] =
          *(const float4*)(W + (size_t)(e0 + e) * DD + k0 + kq * 4);
    }
#pragma unroll
    for (int it = 0; it < 2; ++it) {
      int f4 = tid + it * 256;
      int kk = f4 >> 4, lq = f4 & 15;
      *(float4*)&Bf[kk * 68 + lq * 4] =
          *(const float4*)(Ub + (size_t)(k0 + kk) * LL + l0 + lq * 4);
    }
    __syncthreads();
    bf16x8 afr[2], bfr[4];
#pragma unroll
    for (int te = 0; te < 2; ++te) {
      const float* src = &Af[(w * 32 + te * 16 + m16) * 36 + quad * 8];
      bf16x8 t;
#pragma unroll
      for (int j = 0; j < 8; ++j) t[j] = (__bf16)src[j];
      afr[te] = t;
    }
#pragma unroll
    for (int tl = 0; tl < 4; ++tl) {
      bf16x8 t;
#pragma unroll
      for (int j = 0; j < 8; ++j) t[j] = (__bf16)Bf[(quad * 8 + j) * 68 + tl * 16 + m16];
      bfr[tl] = t;
    }
#pragma unroll
    for (int te = 0; te < 2; ++te)
#pragma unroll
      for (int tl = 0; tl < 4; ++tl)
        acc[te][tl] = __builtin_amdgcn_mfma_f32_16x16x32_bf16(afr[te], bfr[tl], acc[te][tl], 0, 0, 0);
  }

#pragma unroll
  for (int te = 0; te < 2; ++te) {
#pragma unroll
    for (int tl = 0; tl < 4; ++tl) {
      int col = l0 + tl * 16 + m16;
#pragma unroll
      for (int r = 0; r < 4; ++r) {
        int e = e0 + w * 32 + te * 16 + quad * 4 + r;
        float v = acc[te][tl][r];
        if (e < DD) xpre[((size_t)b * DD + e) * LL + col] = v;
        else        zb[((size_t)b * DD + (e - DD)) * LL + col] = v;
      }
    }
  }
}

// ---------------- K2: depthwise conv == 3-tap along d, weights per l ----------------
__global__ __launch_bounds__(256) void k2_conv(
    const float* __restrict__ xpre, const float* __restrict__ cw,
    const float* __restrict__ cb, float* __restrict__ xo) {
  const int bd = blockIdx.x;       // b*256 + d
  const int d = bd & 255;
  const size_t row = (size_t)bd * LL;
  const float* r1 = xpre + row;
  const bool has0 = d > 0, has2 = d < DD - 1;
  for (int j = threadIdx.x; j < LL; j += 256) {
    float w0 = cw[j * 9 + 3], w1 = cw[j * 9 + 4], w2 = cw[j * 9 + 5];
    float v = cb[j] + r1[j] * w1;
    if (has0) v += r1[j - LL] * w0;
    if (has2) v += r1[j + LL] * w2;
    xo[row + j] = v;
  }
}

// ---------------- K3: x_proj GEMM, 6 rows/block, no LDS / no barriers ----------
__global__ __launch_bounds__(256) void k3_xproj(
    const float* __restrict__ xc,
    const float* __restrict__ xpw, const float* __restrict__ xpwB,
    float* __restrict__ dtr, float* __restrict__ gB, float* __restrict__ gC) {
  const int tid = threadIdx.x;
  const int l   = blockIdx.x * 256 + tid;
  const int b   = blockIdx.y;
  const int zz  = blockIdx.z;            // dir*8 + rg
  const int dir = zz >> 3, rg = zz & 7;
  const int rbase = rg * 6;
  const float* W = (dir ? xpwB : xpw) + (size_t)rbase * DD;   // 6 rows x 256
  const float* xcol = xc + (size_t)b * DD * LL + l;

  float acc[6] = {0.f, 0.f, 0.f, 0.f, 0.f, 0.f};

#pragma unroll 8
  for (int d = 0; d < DD; ++d) {
    float xv = xcol[(size_t)d * LL];
#pragma unroll
    for (int i = 0; i < 6; ++i) acc[i] += W[i * DD + d] * xv;
  }

  const size_t ob = ((size_t)dir * BN + b);
#pragma unroll
  for (int i = 0; i < 6; ++i) {
    int r = rbase + i;
    if (r < 16)
      dtr[(ob * 16 + r) * LL + l] = acc[i];
    else if (r < 32)
      gB[(ob * NS + (r - 16)) * LL + l] = acc[i];
    else
      gC[(ob * NS + (r - 32)) * LL + l] = acc[i];
  }
}

// ---------------- K3b: dt_proj + softplus -> gdelta; dtr register-cached ----------
__global__ __launch_bounds__(256) void k3b_dtproj(
    const float* __restrict__ dtr,
    const float* __restrict__ dtw, const float* __restrict__ dtwB,
    const float* __restrict__ dtb,
    float* __restrict__ gdelta) {
  const int tid = threadIdx.x;
  const int l   = blockIdx.x * 256 + tid;
  const int b   = blockIdx.y & 3;
  const int dir = blockIdx.y >> 2;
  const int d0  = blockIdx.z * 64;
  const size_t ob = ((size_t)dir * BN + b);
  const float* dw = (dir ? dtwB : dtw);

  float tr[16];
#pragma unroll
  for (int r = 0; r < 16; ++r) tr[r] = dtr[(ob * 16 + r) * LL + l];

#pragma unroll 4
  for (int d = d0; d < d0 + 64; ++d) {
    float acc = dtb[d];
#pragma unroll
    for (int r = 0; r < 16; ++r) acc += dw[d * 16 + r] * tr[r];
    gdelta[(ob * DD + d) * LL + l] = softplus_f(acc);
  }
}

// ---------------- K4: scan pass A — full LDS staging (dl, dl*x, B); exp2 ----------
// grid.x = 31: chunk 31's (P,q) is never needed by k5's exclusive prefix.
__global__ __launch_bounds__(256) void k4_scanA(
    const float* __restrict__ gdelta, const float* __restrict__ x,
    const float* __restrict__ gB,
    const float* __restrict__ Alog, const float* __restrict__ AlogB,
    float* __restrict__ Pbuf, float* __restrict__ qbuf) {
  __shared__ float sdl[16 * SP];
  __shared__ float sdx[16 * SP];   // delta * u (u flipped for dir=1)
  __shared__ float sB[16 * SP];
  const int s = blockIdx.x;
  const int dbase = blockIdx.y * 16;
  const int dir = blockIdx.z >> 2, b = blockIdx.z & 3;
  const int t0 = s * CT;
  const int tid = threadIdx.x;

  for (int idx = tid; idx < 16 * 32; idx += 256) {
    int row = idx >> 5, q = idx & 31;
    float4 dl = *(const float4*)(gdelta + (((size_t)dir * BN + b) * DD + dbase + row) * LL + t0 + q * 4);
    float4 xv;
    if (dir == 0) {
      xv = *(const float4*)(x + ((size_t)b * DD + dbase + row) * LL + t0 + q * 4);
    } else {
      const float* xrow = x + ((size_t)b * DD + dbase + row) * LL;
      float4 t = *(const float4*)(xrow + (LL - 4 - t0 - q * 4));
      xv = make_float4(t.w, t.z, t.y, t.x);
    }
    *(float4*)&sdl[row * SP + q * 4] = dl;
    *(float4*)&sdx[row * SP + q * 4] =
        make_float4(dl.x * xv.x, dl.y * xv.y, dl.z * xv.z, dl.w * xv.w);
    *(float4*)&sB[row * SP + q * 4] =
        *(const float4*)(gB + (((size_t)dir * BN + b) * NS + row) * LL + t0 + q * 4);
  }
  __syncthreads();

  const int g = tid >> 4, n = tid & 15;
  const int d = dbase + g;
  const float An2 = -__expf((dir ? AlogB : Alog)[d * NS + n]) * LOG2E;
  float h = 0.f, S = 0.f;
#pragma unroll 4
  for (int jb = 0; jb < CT; jb += 4) {
    float4 dl4 = *(float4*)&sdl[g * SP + jb];
    float4 dx4 = *(float4*)&sdx[g * SP + jb];
    float4 B4  = *(float4*)&sB[n * SP + jb];
    h = h * __builtin_amdgcn_exp2f(dl4.x * An2) + dx4.x * B4.x;
    h = h * __builtin_amdgcn_exp2f(dl4.y * An2) + dx4.y * B4.y;
    h = h * __builtin_amdgcn_exp2f(dl4.z * An2) + dx4.z * B4.z;
    h = h * __builtin_amdgcn_exp2f(dl4.w * An2) + dx4.w * B4.w;
    S += dl4.x + dl4.y + dl4.z + dl4.w;
  }
  const size_t pidx = ((((size_t)dir * BN + b) * DD + d) * NCH + s) * NS + n;
  Pbuf[pidx] = __builtin_amdgcn_exp2f(An2 * S);
  qbuf[pidx] = h;
}

// ---------------- K5: middle scan over chunks ----------------
__global__ __launch_bounds__(256) void k5_mid(
    const float* __restrict__ Pbuf, float* __restrict__ qbuf) {
  int id = blockIdx.x * 256 + threadIdx.x;
  int n = id & 15;
  int d = (id >> 4) & 255;
  int rb = id >> 12;
  size_t base = (((size_t)rb * DD + d) * NCH) * NS + n;
  float h = 0.f;
  for (int s = 0; s < NCH; ++s) {
    size_t idx = base + (size_t)s * NS;
    float Pv = Pbuf[idx];   // s=31: garbage, result discarded
    float qv = qbuf[idx];
    qbuf[idx] = h;          // exclusive prefix: state at chunk start
    h = h * Pv + qv;
  }
}

// ---------------- K6: scan pass C — R4 structure (full staging, stride-17 ylds,
//                     16-step batches) + exp2-folded An ----------------
__global__ __launch_bounds__(256) void k6_scanC(
    const float* __restrict__ gdelta, const float* __restrict__ x,
    const float* __restrict__ gB, const float* __restrict__ gC,
    const float* __restrict__ zb,
    const float* __restrict__ Alog, const float* __restrict__ AlogB,
    const float* __restrict__ Dvec, const float* __restrict__ DvecB,
    const float* __restrict__ hstart,
    float* __restrict__ y, float* __restrict__ yb) {
  __shared__ float sdl[16 * SP];
  __shared__ float sx[16 * SP];
  __shared__ float sB[16 * SP];
  __shared__ float sC[16 * SP];
  __shared__ float ylds[16 * 16 * 17];   // [g][n][step-in-batch], stride 17
  const int s = blockIdx.x;
  const int dbase = blockIdx.y * 16;
  const int dir = blockIdx.z >> 2, b = blockIdx.z & 3;
  const int t0 = s * CT;
  const int tid = threadIdx.x;

  for (int idx = tid; idx < 16 * 32; idx += 256) {
    int row = idx >> 5, q = idx & 31;
    *(float4*)&sdl[row * SP + q * 4] =
        *(const float4*)(gdelta + (((size_t)dir * BN + b) * DD + dbase + row) * LL + t0 + q * 4);
    float4 xv;
    if (dir == 0) {
      xv = *(const float4*)(x + ((size_t)b * DD + dbase + row) * LL + t0 + q * 4);
    } else {
      const float* xrow = x + ((size_t)b * DD + dbase + row) * LL;
      float4 t = *(const float4*)(xrow + (LL - 4 - t0 - q * 4));
      xv = make_float4(t.w, t.z, t.y, t.x);
    }
    *(float4*)&sx[row * SP + q * 4] = xv;
    *(float4*)&sB[row * SP + q * 4] =
        *(const float4*)(gB + (((size_t)dir * BN + b) * NS + row) * LL + t0 + q * 4);
    *(float4*)&sC[row * SP + q * 4] =
        *(const float4*)(gC + (((size_t)dir * BN + b) * NS + row) * LL + t0 + q * 4);
  }
  __syncthreads();

  const int g = tid >> 4, n = tid & 15;
  const int d = dbase + g;
  const float An2 = -__expf((dir ? AlogB : Alog)[d * NS + n]) * LOG2E;
  const float Dd = (dir ? DvecB : Dvec)[d];
  const size_t pidx = ((((size_t)dir * BN + b) * DD + d) * NCH + s) * NS + n;
  float h = hstart[pidx];
  float* dst = (dir ? yb : y) + ((size_t)b * DD + d) * LL;
  const float* zrow = zb + ((size_t)b * DD + d) * LL;
  const int yrow = (g * 16 + n) * 17;

  for (int jb = 0; jb < CT; jb += 16) {
#pragma unroll
    for (int q = 0; q < 4; ++q) {
      int j4 = jb + q * 4;
      float4 dl4 = *(float4*)&sdl[g * SP + j4];
      float4 x4  = *(float4*)&sx[g * SP + j4];
      float4 B4  = *(float4*)&sB[n * SP + j4];
      float4 C4  = *(float4*)&sC[n * SP + j4];
      h = h * __builtin_amdgcn_exp2f(dl4.x * An2) + (dl4.x * x4.x) * B4.x; ylds[yrow + q * 4 + 0] = h * C4.x;
      h = h * __builtin_amdgcn_exp2f(dl4.y * An2) + (dl4.y * x4.y) * B4.y; ylds[yrow + q * 4 + 1] = h * C4.y;
      h = h * __builtin_amdgcn_exp2f(dl4.z * An2) + (dl4.z * x4.z) * B4.z; ylds[yrow + q * 4 + 2] = h * C4.z;
      h = h * __builtin_amdgcn_exp2f(dl4.w * An2) + (dl4.w * x4.w) * B4.w; ylds[yrow + q * 4 + 3] = h * C4.w;
    }
    // intra-wave transpose reduction: lane n sums over m for step t = jb + n
    float ysum = 0.f;
#pragma unroll
    for (int m = 0; m < 16; ++m) ysum += ylds[(g * 16 + m) * 17 + n];
    int t = jb + n;
    float xv = sx[g * SP + t];
    float zv = zrow[t0 + t];
    dst[t0 + t] = (ysum + Dd * xv) * silu_f(zv);
  }
}

// ---------------- K7: dual LayerNorm + double SiLU gate + flip-add ----------------
__global__ __launch_bounds__(256) void k7_final(
    const float* __restrict__ y, const float* __restrict__ yb,
    const float* __restrict__ zb,
    const float* __restrict__ lnw, const float* __restrict__ lnb,
    const float* __restrict__ ln1w, const float* __restrict__ ln1b,
    float* __restrict__ out) {
  __shared__ float sy[LL];
  __shared__ float syb[LL];
  __shared__ float rsum[4][4];
  const int row = blockIdx.x;
  const int tid = threadIdx.x;
  const size_t base = (size_t)row * LL;
  float s1y = 0.f, s2y = 0.f, s1b = 0.f, s2b = 0.f;
  for (int j = tid * 4; j < LL; j += 1024) {
    float4 v = *(const float4*)(y + base + j);
    *(float4*)&sy[j] = v;
    s1y += v.x + v.y + v.z + v.w;
    s2y += v.x * v.x + v.y * v.y + v.z * v.z + v.w * v.w;
    float4 w = *(const float4*)(yb + base + j);
    *(float4*)&syb[j] = w;
    s1b += w.x + w.y + w.z + w.w;
    s2b += w.x * w.x + w.y * w.y + w.z * w.z + w.w * w.w;
  }
#pragma unroll
  for (int m = 1; m < 64; m <<= 1) {
    s1y += __shfl_xor(s1y, m); s2y += __shfl_xor(s2y, m);
    s1b += __shfl_xor(s1b, m); s2b += __shfl_xor(s2b, m);
  }
  int wv = tid >> 6;
  if ((tid & 63) == 0) { rsum[wv][0] = s1y; rsum[wv][1] = s2y; rsum[wv][2] = s1b; rsum[wv][3] = s2b; }
  __syncthreads();
  float t1y = rsum[0][0] + rsum[1][0] + rsum[2][0] + rsum[3][0];
  float t2y = rsum[0][1] + rsum[1][1] + rsum[2][1] + rsum[3][1];
  float t1b = rsum[0][2] + rsum[1][2] + rsum[2][2] + rsum[3][2];
  float t2b = rsum[0][3] + rsum[1][3] + rsum[2][3] + rsum[3][3];
  const float inv = 1.f / (float)LL;
  float mY = t1y * inv; float vY = t2y * inv - mY * mY; float rY = rsqrtf(vY + 1e-5f);
  float mB = t1b * inv; float vB = t2b * inv - mB * mB; float rB = rsqrtf(vB + 1e-5f);
  for (int j = tid; j < LL; j += 256) {
    int jr = LL - 1 - j;
    float a  = (sy[j]  - mY) * rY * lnw[j]   + lnb[j];
    float g1 = silu_f(zb[base + j]);
    float bv = (syb[jr] - mB) * rB * ln1w[jr] + ln1b[jr];
    float g2 = silu_f(zb[base + jr]);
    out[base + j] = a * g1 + bv * g2;
  }
}

extern "C" void kernel_launch(void* const* d_in, const int* in_sizes, int n_in,
                              void* d_out, int out_size, void* d_ws, size_t ws_size,
                              hipStream_t stream) {
  const float* u     = (const float*)d_in[0];
  const float* inw   = (const float*)d_in[1];
  const float* cw    = (const float*)d_in[2];
  const float* cb    = (const float*)d_in[3];
  const float* xpw   = (const float*)d_in[4];
  const float* dtw   = (const float*)d_in[5];
  const float* dtb   = (const float*)d_in[6];
  const float* Alog  = (const float*)d_in[7];
  const float* Dv    = (const float*)d_in[8];
  const float* xpwB  = (const float*)d_in[9];
  const float* dtwB  = (const float*)d_in[10];
  const float* AlogB = (const float*)d_in[11];
  const float* DvB   = (const float*)d_in[12];
  const float* lnw   = (const float*)d_in[13];
  const float* lnb   = (const float*)d_in[14];
  const float* ln1w  = (const float*)d_in[15];
  const float* ln1b  = (const float*)d_in[16];
  float* out = (float*)d_out;

  float* ws = (float*)d_ws;
  const size_t SZ = (size_t)BN * DD * LL;        // 4,194,304 floats
  float* xpre   = ws;
  float* zb     = ws + SZ;
  float* xc     = ws + 2 * SZ;
  float* gdelta = ws + 3 * SZ;        // 2 dirs
  float* gB     = ws + 5 * SZ;
  float* gC     = gB + SZ / 8;
  float* Pbuf   = gC + SZ / 8;
  float* qbuf   = Pbuf + SZ / 4;      // becomes hstart after k5_mid
  float* ybbuf  = qbuf + SZ / 4;
  float* ybuf   = xpre;               // alias: xpre dead after k2
  float* dtr    = ybbuf;              // alias: dtr dead before k6 writes ybbuf

  k1_mfma<<<dim3(64, 4, 4), 256, 0, stream>>>(inw, u, xpre, zb);
  k2_conv<<<1024, 256, 0, stream>>>(xpre, cw, cb, xc);
  k3_xproj<<<dim3(16, 4, 16), 256, 0, stream>>>(xc, xpw, xpwB, dtr, gB, gC);
  k3b_dtproj<<<dim3(16, 8, 4), 256, 0, stream>>>(dtr, dtw, dtwB, dtb, gdelta);
  k4_scanA<<<dim3(NCH - 1, 16, 8), 256, 0, stream>>>(gdelta, xc, gB, Alog, AlogB, Pbuf, qbuf);
  k5_mid<<<128, 256, 0, stream>>>(Pbuf, qbuf);
  k6_scanC<<<dim3(NCH, 16, 8), 256, 0, stream>>>(gdelta, xc, gB, gC, zb, Alog, AlogB,
                                                 Dv, DvB, qbuf, ybuf, ybbuf);
  k7_final<<<1024, 256, 0, stream>>>(ybuf, ybbuf, zb, lnw, lnb, ln1w, ln1b, out);
}

// Round 11
// 306.838 us; speedup vs baseline: 1.5115x; 1.0151x over previous
//
#include <hip/hip_runtime.h>
#include <math.h>

#define BN 4
#define DD 256
#define LL 4096
#define NS 16
#define NCH 64   // scan chunks
#define CT 64    // chunk length (NCH*CT == LL)
#define SP 68    // CT + 4 pad
#define LOG2E 1.4426950408889634f

typedef __bf16 bf16x8 __attribute__((ext_vector_type(8)));
typedef float f32x4 __attribute__((ext_vector_type(4)));

__device__ __forceinline__ float softplus_f(float v) {
  return v > 20.f ? v : log1pf(__expf(v));
}
__device__ __forceinline__ float silu_f(float v) {
  return v / (1.f + __expf(-v));
}

// ---------------- K1: MFMA bf16 GEMM with inline f32->bf16 conversion ----------------
__global__ __launch_bounds__(256) void k1_mfma(
    const float* __restrict__ W, const float* __restrict__ u,
    float* __restrict__ xpre, float* __restrict__ zb) {
  __shared__ float Af[128 * 36];   // [e][k] f32, stride 36
  __shared__ float Bf[32 * 68];    // [k][l] f32, stride 68
  const int l0 = blockIdx.x * 64;
  const int e0 = blockIdx.y * 128;
  const int b  = blockIdx.z;
  const int tid = threadIdx.x;
  const int lane = tid & 63, w = tid >> 6;
  const int m16 = lane & 15, quad = lane >> 4;

  f32x4 acc[2][4];
#pragma unroll
  for (int i = 0; i < 2; ++i)
#pragma unroll
    for (int j = 0; j < 4; ++j) acc[i][j] = (f32x4){0.f, 0.f, 0.f, 0.f};

  const float* Ub = u + (size_t)b * DD * LL;

  for (int k0 = 0; k0 < DD; k0 += 32) {
    if (k0) __syncthreads();
#pragma unroll
    for (int it = 0; it < 4; ++it) {
      int f4 = tid + it * 256;
      int e = f4 >> 3, kq = f4 & 7;
      *(float4*)&Af[e * 36 + kq * 4] =
          *(const float4*)(W + (size_t)(e0 + e) * DD + k0 + kq * 4);
    }
#pragma unroll
    for (int it = 0; it < 2; ++it) {
      int f4 = tid + it * 256;
      int kk = f4 >> 4, lq = f4 & 15;
      *(float4*)&Bf[kk * 68 + lq * 4] =
          *(const float4*)(Ub + (size_t)(k0 + kk) * LL + l0 + lq * 4);
    }
    __syncthreads();
    bf16x8 afr[2], bfr[4];
#pragma unroll
    for (int te = 0; te < 2; ++te) {
      const float* src = &Af[(w * 32 + te * 16 + m16) * 36 + quad * 8];
      bf16x8 t;
#pragma unroll
      for (int j = 0; j < 8; ++j) t[j] = (__bf16)src[j];
      afr[te] = t;
    }
#pragma unroll
    for (int tl = 0; tl < 4; ++tl) {
      bf16x8 t;
#pragma unroll
      for (int j = 0; j < 8; ++j) t[j] = (__bf16)Bf[(quad * 8 + j) * 68 + tl * 16 + m16];
      bfr[tl] = t;
    }
#pragma unroll
    for (int te = 0; te < 2; ++te)
#pragma unroll
      for (int tl = 0; tl < 4; ++tl)
        acc[te][tl] = __builtin_amdgcn_mfma_f32_16x16x32_bf16(afr[te], bfr[tl], acc[te][tl], 0, 0, 0);
  }

#pragma unroll
  for (int te = 0; te < 2; ++te) {
#pragma unroll
    for (int tl = 0; tl < 4; ++tl) {
      int col = l0 + tl * 16 + m16;
#pragma unroll
      for (int r = 0; r < 4; ++r) {
        int e = e0 + w * 32 + te * 16 + quad * 4 + r;
        float v = acc[te][tl][r];
        if (e < DD) xpre[((size_t)b * DD + e) * LL + col] = v;
        else        zb[((size_t)b * DD + (e - DD)) * LL + col] = v;
      }
    }
  }
}

// ---------------- K2: depthwise conv == 3-tap along d, weights per l ----------------
__global__ __launch_bounds__(256) void k2_conv(
    const float* __restrict__ xpre, const float* __restrict__ cw,
    const float* __restrict__ cb, float* __restrict__ xo) {
  const int bd = blockIdx.x;       // b*256 + d
  const int d = bd & 255;
  const size_t row = (size_t)bd * LL;
  const float* r1 = xpre + row;
  const bool has0 = d > 0, has2 = d < DD - 1;
  for (int j = threadIdx.x; j < LL; j += 256) {
    float w0 = cw[j * 9 + 3], w1 = cw[j * 9 + 4], w2 = cw[j * 9 + 5];
    float v = cb[j] + r1[j] * w1;
    if (has0) v += r1[j - LL] * w0;
    if (has2) v += r1[j + LL] * w2;
    xo[row + j] = v;
  }
}

// ---------------- K3: x_proj GEMM, 6 rows/block, no LDS / no barriers ----------
__global__ __launch_bounds__(256) void k3_xproj(
    const float* __restrict__ xc,
    const float* __restrict__ xpw, const float* __restrict__ xpwB,
    float* __restrict__ dtr, float* __restrict__ gB, float* __restrict__ gC) {
  const int tid = threadIdx.x;
  const int l   = blockIdx.x * 256 + tid;
  const int b   = blockIdx.y;
  const int zz  = blockIdx.z;            // dir*8 + rg
  const int dir = zz >> 3, rg = zz & 7;
  const int rbase = rg * 6;
  const float* W = (dir ? xpwB : xpw) + (size_t)rbase * DD;   // 6 rows x 256
  const float* xcol = xc + (size_t)b * DD * LL + l;

  float acc[6] = {0.f, 0.f, 0.f, 0.f, 0.f, 0.f};

#pragma unroll 8
  for (int d = 0; d < DD; ++d) {
    float xv = xcol[(size_t)d * LL];
#pragma unroll
    for (int i = 0; i < 6; ++i) acc[i] += W[i * DD + d] * xv;
  }

  const size_t ob = ((size_t)dir * BN + b);
#pragma unroll
  for (int i = 0; i < 6; ++i) {
    int r = rbase + i;
    if (r < 16)
      dtr[(ob * 16 + r) * LL + l] = acc[i];
    else if (r < 32)
      gB[(ob * NS + (r - 16)) * LL + l] = acc[i];
    else
      gC[(ob * NS + (r - 32)) * LL + l] = acc[i];
  }
}

// ---------------- K3b: dt_proj + softplus -> gdelta; dtr register-cached ----------
__global__ __launch_bounds__(256) void k3b_dtproj(
    const float* __restrict__ dtr,
    const float* __restrict__ dtw, const float* __restrict__ dtwB,
    const float* __restrict__ dtb,
    float* __restrict__ gdelta) {
  const int tid = threadIdx.x;
  const int l   = blockIdx.x * 256 + tid;
  const int b   = blockIdx.y & 3;
  const int dir = blockIdx.y >> 2;
  const int d0  = blockIdx.z * 64;
  const size_t ob = ((size_t)dir * BN + b);
  const float* dw = (dir ? dtwB : dtw);

  float tr[16];
#pragma unroll
  for (int r = 0; r < 16; ++r) tr[r] = dtr[(ob * 16 + r) * LL + l];

#pragma unroll 4
  for (int d = d0; d < d0 + 64; ++d) {
    float acc = dtb[d];
#pragma unroll
    for (int r = 0; r < 16; ++r) acc += dw[d * 16 + r] * tr[r];
    gdelta[(ob * DD + d) * LL + l] = softplus_f(acc);
  }
}

// ---------------- K4: scan pass A — full LDS staging (dl, dl*x, B); exp2 ----------
// grid.x = NCH-1: last chunk's (P,q) is never needed by k5's exclusive prefix.
__global__ __launch_bounds__(256) void k4_scanA(
    const float* __restrict__ gdelta, const float* __restrict__ x,
    const float* __restrict__ gB,
    const float* __restrict__ Alog, const float* __restrict__ AlogB,
    float* __restrict__ Pbuf, float* __restrict__ qbuf) {
  __shared__ float sdl[16 * SP];
  __shared__ float sdx[16 * SP];   // delta * u (u flipped for dir=1)
  __shared__ float sB[16 * SP];
  const int s = blockIdx.x;
  const int dbase = blockIdx.y * 16;
  const int dir = blockIdx.z >> 2, b = blockIdx.z & 3;
  const int t0 = s * CT;
  const int tid = threadIdx.x;

  {
    int row = tid >> 4, q = tid & 15;   // 16 rows x 16 float4s == 256 threads
    float4 dl = *(const float4*)(gdelta + (((size_t)dir * BN + b) * DD + dbase + row) * LL + t0 + q * 4);
    float4 xv;
    if (dir == 0) {
      xv = *(const float4*)(x + ((size_t)b * DD + dbase + row) * LL + t0 + q * 4);
    } else {
      const float* xrow = x + ((size_t)b * DD + dbase + row) * LL;
      float4 t = *(const float4*)(xrow + (LL - 4 - t0 - q * 4));
      xv = make_float4(t.w, t.z, t.y, t.x);
    }
    *(float4*)&sdl[row * SP + q * 4] = dl;
    *(float4*)&sdx[row * SP + q * 4] =
        make_float4(dl.x * xv.x, dl.y * xv.y, dl.z * xv.z, dl.w * xv.w);
    *(float4*)&sB[row * SP + q * 4] =
        *(const float4*)(gB + (((size_t)dir * BN + b) * NS + row) * LL + t0 + q * 4);
  }
  __syncthreads();

  const int g = tid >> 4, n = tid & 15;
  const int d = dbase + g;
  const float An2 = -__expf((dir ? AlogB : Alog)[d * NS + n]) * LOG2E;
  float h = 0.f, S = 0.f;
#pragma unroll 4
  for (int jb = 0; jb < CT; jb += 4) {
    float4 dl4 = *(float4*)&sdl[g * SP + jb];
    float4 dx4 = *(float4*)&sdx[g * SP + jb];
    float4 B4  = *(float4*)&sB[n * SP + jb];
    h = h * __builtin_amdgcn_exp2f(dl4.x * An2) + dx4.x * B4.x;
    h = h * __builtin_amdgcn_exp2f(dl4.y * An2) + dx4.y * B4.y;
    h = h * __builtin_amdgcn_exp2f(dl4.z * An2) + dx4.z * B4.z;
    h = h * __builtin_amdgcn_exp2f(dl4.w * An2) + dx4.w * B4.w;
    S += dl4.x + dl4.y + dl4.z + dl4.w;
  }
  const size_t pidx = ((((size_t)dir * BN + b) * DD + d) * NCH + s) * NS + n;
  Pbuf[pidx] = __builtin_amdgcn_exp2f(An2 * S);
  qbuf[pidx] = h;
}

// ---------------- K5: middle scan over chunks ----------------
__global__ __launch_bounds__(256) void k5_mid(
    const float* __restrict__ Pbuf, float* __restrict__ qbuf) {
  int id = blockIdx.x * 256 + threadIdx.x;
  int n = id & 15;
  int d = (id >> 4) & 255;
  int rb = id >> 12;
  size_t base = (((size_t)rb * DD + d) * NCH) * NS + n;
  float h = 0.f;
  for (int s = 0; s < NCH; ++s) {
    size_t idx = base + (size_t)s * NS;
    float Pv = Pbuf[idx];   // s=NCH-1: garbage, result discarded
    float qv = qbuf[idx];
    qbuf[idx] = h;          // exclusive prefix: state at chunk start
    h = h * Pv + qv;
  }
}

// ---------------- K6: scan pass C — full staging, stride-17 ylds, 16-step
//                     batches, exp2-folded An; CT=64 for 4 blocks/CU ----------
__global__ __launch_bounds__(256) void k6_scanC(
    const float* __restrict__ gdelta, const float* __restrict__ x,
    const float* __restrict__ gB, const float* __restrict__ gC,
    const float* __restrict__ zb,
    const float* __restrict__ Alog, const float* __restrict__ AlogB,
    const float* __restrict__ Dvec, const float* __restrict__ DvecB,
    const float* __restrict__ hstart,
    float* __restrict__ y, float* __restrict__ yb) {
  __shared__ float sdl[16 * SP];
  __shared__ float sx[16 * SP];
  __shared__ float sB[16 * SP];
  __shared__ float sC[16 * SP];
  __shared__ float ylds[16 * 16 * 17];   // [g][n][step-in-batch], stride 17
  const int s = blockIdx.x;
  const int dbase = blockIdx.y * 16;
  const int dir = blockIdx.z >> 2, b = blockIdx.z & 3;
  const int t0 = s * CT;
  const int tid = threadIdx.x;

  {
    int row = tid >> 4, q = tid & 15;   // 16 rows x 16 float4s == 256 threads
    *(float4*)&sdl[row * SP + q * 4] =
        *(const float4*)(gdelta + (((size_t)dir * BN + b) * DD + dbase + row) * LL + t0 + q * 4);
    float4 xv;
    if (dir == 0) {
      xv = *(const float4*)(x + ((size_t)b * DD + dbase + row) * LL + t0 + q * 4);
    } else {
      const float* xrow = x + ((size_t)b * DD + dbase + row) * LL;
      float4 t = *(const float4*)(xrow + (LL - 4 - t0 - q * 4));
      xv = make_float4(t.w, t.z, t.y, t.x);
    }
    *(float4*)&sx[row * SP + q * 4] = xv;
    *(float4*)&sB[row * SP + q * 4] =
        *(const float4*)(gB + (((size_t)dir * BN + b) * NS + row) * LL + t0 + q * 4);
    *(float4*)&sC[row * SP + q * 4] =
        *(const float4*)(gC + (((size_t)dir * BN + b) * NS + row) * LL + t0 + q * 4);
  }
  __syncthreads();

  const int g = tid >> 4, n = tid & 15;
  const int d = dbase + g;
  const float An2 = -__expf((dir ? AlogB : Alog)[d * NS + n]) * LOG2E;
  const float Dd = (dir ? DvecB : Dvec)[d];
  const size_t pidx = ((((size_t)dir * BN + b) * DD + d) * NCH + s) * NS + n;
  float h = hstart[pidx];
  float* dst = (dir ? yb : y) + ((size_t)b * DD + d) * LL;
  const float* zrow = zb + ((size_t)b * DD + d) * LL;
  const int yrow = (g * 16 + n) * 17;

  for (int jb = 0; jb < CT; jb += 16) {
#pragma unroll
    for (int q = 0; q < 4; ++q) {
      int j4 = jb + q * 4;
      float4 dl4 = *(float4*)&sdl[g * SP + j4];
      float4 x4  = *(float4*)&sx[g * SP + j4];
      float4 B4  = *(float4*)&sB[n * SP + j4];
      float4 C4  = *(float4*)&sC[n * SP + j4];
      h = h * __builtin_amdgcn_exp2f(dl4.x * An2) + (dl4.x * x4.x) * B4.x; ylds[yrow + q * 4 + 0] = h * C4.x;
      h = h * __builtin_amdgcn_exp2f(dl4.y * An2) + (dl4.y * x4.y) * B4.y; ylds[yrow + q * 4 + 1] = h * C4.y;
      h = h * __builtin_amdgcn_exp2f(dl4.z * An2) + (dl4.z * x4.z) * B4.z; ylds[yrow + q * 4 + 2] = h * C4.z;
      h = h * __builtin_amdgcn_exp2f(dl4.w * An2) + (dl4.w * x4.w) * B4.w; ylds[yrow + q * 4 + 3] = h * C4.w;
    }
    // intra-wave transpose reduction: lane n sums over m for step t = jb + n
    float ysum = 0.f;
#pragma unroll
    for (int m = 0; m < 16; ++m) ysum += ylds[(g * 16 + m) * 17 + n];
    int t = jb + n;
    float xv = sx[g * SP + t];
    float zv = zrow[t0 + t];
    dst[t0 + t] = (ysum + Dd * xv) * silu_f(zv);
  }
}

// ---------------- K7: dual LayerNorm + double SiLU gate + flip-add ----------------
__global__ __launch_bounds__(256) void k7_final(
    const float* __restrict__ y, const float* __restrict__ yb,
    const float* __restrict__ zb,
    const float* __restrict__ lnw, const float* __restrict__ lnb,
    const float* __restrict__ ln1w, const float* __restrict__ ln1b,
    float* __restrict__ out) {
  __shared__ float sy[LL];
  __shared__ float syb[LL];
  __shared__ float rsum[4][4];
  const int row = blockIdx.x;
  const int tid = threadIdx.x;
  const size_t base = (size_t)row * LL;
  float s1y = 0.f, s2y = 0.f, s1b = 0.f, s2b = 0.f;
  for (int j = tid * 4; j < LL; j += 1024) {
    float4 v = *(const float4*)(y + base + j);
    *(float4*)&sy[j] = v;
    s1y += v.x + v.y + v.z + v.w;
    s2y += v.x * v.x + v.y * v.y + v.z * v.z + v.w * v.w;
    float4 w = *(const float4*)(yb + base + j);
    *(float4*)&syb[j] = w;
    s1b += w.x + w.y + w.z + w.w;
    s2b += w.x * w.x + w.y * w.y + w.z * w.z + w.w * w.w;
  }
#pragma unroll
  for (int m = 1; m < 64; m <<= 1) {
    s1y += __shfl_xor(s1y, m); s2y += __shfl_xor(s2y, m);
    s1b += __shfl_xor(s1b, m); s2b += __shfl_xor(s2b, m);
  }
  int wv = tid >> 6;
  if ((tid & 63) == 0) { rsum[wv][0] = s1y; rsum[wv][1] = s2y; rsum[wv][2] = s1b; rsum[wv][3] = s2b; }
  __syncthreads();
  float t1y = rsum[0][0] + rsum[1][0] + rsum[2][0] + rsum[3][0];
  float t2y = rsum[0][1] + rsum[1][1] + rsum[2][1] + rsum[3][1];
  float t1b = rsum[0][2] + rsum[1][2] + rsum[2][2] + rsum[3][2];
  float t2b = rsum[0][3] + rsum[1][3] + rsum[2][3] + rsum[3][3];
  const float inv = 1.f / (float)LL;
  float mY = t1y * inv; float vY = t2y * inv - mY * mY; float rY = rsqrtf(vY + 1e-5f);
  float mB = t1b * inv; float vB = t2b * inv - mB * mB; float rB = rsqrtf(vB + 1e-5f);
  for (int j = tid; j < LL; j += 256) {
    int jr = LL - 1 - j;
    float a  = (sy[j]  - mY) * rY * lnw[j]   + lnb[j];
    float g1 = silu_f(zb[base + j]);
    float bv = (syb[jr] - mB) * rB * ln1w[jr] + ln1b[jr];
    float g2 = silu_f(zb[base + jr]);
    out[base + j] = a * g1 + bv * g2;
  }
}

extern "C" void kernel_launch(void* const* d_in, const int* in_sizes, int n_in,
                              void* d_out, int out_size, void* d_ws, size_t ws_size,
                              hipStream_t stream) {
  const float* u     = (const float*)d_in[0];
  const float* inw   = (const float*)d_in[1];
  const float* cw    = (const float*)d_in[2];
  const float* cb    = (const float*)d_in[3];
  const float* xpw   = (const float*)d_in[4];
  const float* dtw   = (const float*)d_in[5];
  const float* dtb   = (const float*)d_in[6];
  const float* Alog  = (const float*)d_in[7];
  const float* Dv    = (const float*)d_in[8];
  const float* xpwB  = (const float*)d_in[9];
  const float* dtwB  = (const float*)d_in[10];
  const float* AlogB = (const float*)d_in[11];
  const float* DvB   = (const float*)d_in[12];
  const float* lnw   = (const float*)d_in[13];
  const float* lnb   = (const float*)d_in[14];
  const float* ln1w  = (const float*)d_in[15];
  const float* ln1b  = (const float*)d_in[16];
  float* out = (float*)d_out;

  float* ws = (float*)d_ws;
  const size_t SZ = (size_t)BN * DD * LL;        // 4,194,304 floats
  float* xpre   = ws;
  float* zb     = ws + SZ;
  float* xc     = ws + 2 * SZ;
  float* gdelta = ws + 3 * SZ;        // 2 dirs
  float* gB     = ws + 5 * SZ;
  float* gC     = gB + SZ / 8;
  float* Pbuf   = gC + SZ / 8;        // 2*4*256*64*16 = SZ/2
  float* qbuf   = Pbuf + SZ / 2;      // becomes hstart after k5_mid
  float* ybbuf  = qbuf + SZ / 2;      // total 7.25*SZ ~ 122 MB
  float* ybuf   = xpre;               // alias: xpre dead after k2
  float* dtr    = ybbuf;              // alias: dtr dead before k6 writes ybbuf

  k1_mfma<<<dim3(64, 4, 4), 256, 0, stream>>>(inw, u, xpre, zb);
  k2_conv<<<1024, 256, 0, stream>>>(xpre, cw, cb, xc);
  k3_xproj<<<dim3(16, 4, 16), 256, 0, stream>>>(xc, xpw, xpwB, dtr, gB, gC);
  k3b_dtproj<<<dim3(16, 8, 4), 256, 0, stream>>>(dtr, dtw, dtwB, dtb, gdelta);
  k4_scanA<<<dim3(NCH - 1, 16, 8), 256, 0, stream>>>(gdelta, xc, gB, Alog, AlogB, Pbuf, qbuf);
  k5_mid<<<128, 256, 0, stream>>>(Pbuf, qbuf);
  k6_scanC<<<dim3(NCH, 16, 8), 256, 0, stream>>>(gdelta, xc, gB, gC, zb, Alog, AlogB,
                                                 Dv, DvB, qbuf, ybuf, ybbuf);
  k7_final<<<1024, 256, 0, stream>>>(ybuf, ybbuf, zb, lnw, lnb, ln1w, ln1b, out);
}